// Round 6
// baseline (887.048 us; speedup 1.0000x reference)
//
#include <hip/hip_runtime.h>

#define TB 512   // batch
#define TT 1024  // time
#define TD 64    // input dim
#define TH 128   // hidden
#define NR 4     // batch rows per block -> 128 blocks, 1 per CU (of 256)

typedef __attribute__((ext_vector_type(8))) short short8;  // 8 bf16 (4 VGPRs)
typedef __attribute__((ext_vector_type(4))) float f32x4;   // MFMA C/D
typedef __attribute__((ext_vector_type(2))) float f32x2;

#define LOG2E 1.44269504f

// fp32 -> bf16 bits, round-to-nearest-even
__device__ __forceinline__ short bfb(float f) {
    unsigned u = __builtin_bit_cast(unsigned, f);
    u = (u + 0x7FFFu + ((u >> 16) & 1u)) >> 16;
    return (short)u;
}

// Barrier with LDS-only drain: global loads/stores stay in flight across it.
#define BAR() asm volatile("s_waitcnt lgkmcnt(0)\n\ts_barrier" ::: "memory")

#define MFMA(a, b, cc) __builtin_amdgcn_mfma_f32_16x16x32_bf16(a, b, cc, 0, 0, 0)

// select v[r], r = s1*2 + s0, via 3 cndmasks (bools precomputed per lane)
__device__ __forceinline__ float ext4(f32x4 v, bool s0, bool s1) {
    float a = s0 ? v[1] : v[0];
    float b = s0 ? v[3] : v[2];
    return s1 ? b : a;
}

// ---------------- phase 1: x -> bf16 fragment order (compact, 4 rows) -------
// ws layout (short8 units): [blk 0..127][t][kt 0..1][e 0..15], e = c*4 + quad
// holds x[blk*4 + c][t][32*kt + 8*quad + j], j=0..7
__global__ __launch_bounds__(256)
void xswz(const float* __restrict__ x, short8* __restrict__ ws) {
    int gid = blockIdx.x * 256 + threadIdx.x;   // 128*1024*2*16 = 4.19M
    int e   = gid & 15;
    int kt  = (gid >> 4) & 1;
    int t   = (gid >> 5) & (TT - 1);
    int blk = gid >> 15;
    int c = e >> 2, quad = e & 3;
    const float* p = x + ((size_t)(blk * NR + c) * TT + t) * TD + 32 * kt + 8 * quad;
    f32x4 a = *(const f32x4*)p;
    f32x4 b = *(const f32x4*)(p + 4);
    short8 f;
    #pragma unroll
    for (int j = 0; j < 4; ++j) { f[j] = bfb(a[j]); f[4 + j] = bfb(b[j]); }
    ws[gid] = f;
}

// ---------------- phase 2: the scan -----------------------------------------
// 128 blocks x 256 threads (4 waves, 1/SIMD). Block owns 4 batch rows.
// Each wave owns 32 gate cols as TWO interleaved 16-col tiles:
//   tile T covers cols {32w + 2i + T, i=0..15}.
// The h B-fragment (ha) is SHARED by both tiles -> per-CU ha ds_reads halve
// vs the 8-wave version; barrier syncs 4 waves; xw loads 4x (not 8x)
// replicated. Lane (c,q) owns 2 adjacent cols 32w+8q+2*(c>>2)+{0,1}, so the
// h-write is one packed ds_write_b32. Everything else as round 5.
template <bool USE_WS>
__global__ __launch_bounds__(256, 1)
void gru_mfma(const float* __restrict__ x, const short8* __restrict__ xw,
              const float* __restrict__ mask,
              const float* __restrict__ w_ih, const float* __restrict__ w_hh,
              const float* __restrict__ b_ih, const float* __restrict__ b_hh,
              const float* __restrict__ Wo, const float* __restrict__ bo,
              float* __restrict__ out)
{
    __shared__ short hbuf[2][4][144];     // h(t) bf16, rows 0..3; 288B row
    __shared__ float mlds[TT][NR];        // mask slice (16 KB)

    const int tid  = threadIdx.x;
    const int w    = tid >> 6;            // 0..3
    const int lane = tid & 63;
    const int c    = lane & 15;
    const int quad = lane >> 4;
    const int Bb   = blockIdx.x * NR;
    const int cb   = c & 3;               // batch row this lane tracks
    const bool s0  = ((c >> 2) & 1) != 0; // extract selectors for reg c>>2
    const bool s1  = ((c >> 3) & 1) != 0;

    // ---- one-time staging ----
    for (int i = tid; i < TT * NR; i += 256) {
        int t = i >> 2, b = i & 3;
        mlds[t][b] = mask[(size_t)(Bb + b) * TT + t];
    }
    for (int i = tid; i < 2 * 4 * 144; i += 256) (&hbuf[0][0][0])[i] = 0;

    // ---- weights -> bf16 fragments, 2 tiles ----
    short8 whh2[2][3][4], wih2[2][3][2], wof[4];
    #pragma unroll
    for (int T = 0; T < 2; ++T) {
        const int jjT = 32 * w + 2 * c + T;
        const int gg[3] = {jjT, TH + jjT, 2 * TH + jjT};
        #pragma unroll
        for (int g = 0; g < 3; ++g) {
            #pragma unroll
            for (int kt = 0; kt < 4; ++kt) {
                const float* p = w_hh + (size_t)gg[g] * TH + 32 * kt + 8 * quad;
                short8 f;
                #pragma unroll
                for (int j = 0; j < 8; ++j) f[j] = bfb(p[j]);
                whh2[T][g][kt] = f;
            }
            #pragma unroll
            for (int kt = 0; kt < 2; ++kt) {
                const float* p = w_ih + (size_t)gg[g] * TD + 32 * kt + 8 * quad;
                short8 f;
                #pragma unroll
                for (int j = 0; j < 8; ++j) f[j] = bfb(p[j]);
                wih2[T][g][kt] = f;
            }
        }
    }
    #pragma unroll
    for (int kt = 0; kt < 4; ++kt) {
        short8 f = {0,0,0,0,0,0,0,0};
        if (c < 2) {
            const float* p = Wo + (size_t)c * TH + 32 * kt + 8 * quad;
            #pragma unroll
            for (int j = 0; j < 8; ++j) f[j] = bfb(p[j]);
        }
        wof[kt] = f;
    }

    // epilogue constants: lane owns cols colL+0 (tile0), colL+1 (tile1)
    const int colL = 32 * w + 8 * quad + 2 * (c >> 2);
    float crK[2], czK[2], binc[2], bhnc[2];
    #pragma unroll
    for (int T = 0; T < 2; ++T) {
        const int mc = colL + T;
        crK[T]  = -LOG2E * (b_ih[mc] + b_hh[mc]);
        czK[T]  = -LOG2E * (b_ih[TH + mc] + b_hh[TH + mc]);
        binc[T] = b_ih[2 * TH + mc];
        bhnc[T] = b_hh[2 * TH + mc];
    }
    const float b0o = bo[0], b1o = bo[1];

    const f32x4 zf4 = {0.f, 0.f, 0.f, 0.f};

    // x access bases — replicated across c-groups (row cb), as round 5
    const short8* xwp  = xw + (size_t)blockIdx.x * (TT * 32) + (cb * 4 + quad);
    const float*  xrow = x + (size_t)(Bb + cb) * TT * TD + 8 * quad;

    short8 xf0[2], xf1[2];
    // frags(0) -> xf0
    if (USE_WS) {
        xf0[0] = xwp[0];
        xf0[1] = xwp[16];
    } else {
        #pragma unroll
        for (int kt = 0; kt < 2; ++kt) {
            f32x4 a = *(const f32x4*)(xrow + 32 * kt);
            f32x4 b = *(const f32x4*)(xrow + 32 * kt + 4);
            short8 f;
            #pragma unroll
            for (int j = 0; j < 4; ++j) { f[j] = bfb(a[j]); f[4 + j] = bfb(b[j]); }
            xf0[kt] = f;
        }
    }

    // xacc(0) from frags(0)
    f32x4 xacA[2][3], xacB[2][3];
    #pragma unroll
    for (int T = 0; T < 2; ++T)
        #pragma unroll
        for (int g = 0; g < 3; ++g) {
            f32x4 a = zf4;
            a = MFMA(wih2[T][g][0], xf0[0], a);
            a = MFMA(wih2[T][g][1], xf0[1], a);
            xacA[T][g] = a;
        }

    // frags(1) -> xf0
    if (USE_WS) {
        xf0[0] = xwp[32];
        xf0[1] = xwp[48];
    } else {
        const float* p = xrow + (size_t)1 * TD;
        #pragma unroll
        for (int kt = 0; kt < 2; ++kt) {
            f32x4 a = *(const f32x4*)(p + 32 * kt);
            f32x4 b = *(const f32x4*)(p + 32 * kt + 4);
            short8 f;
            #pragma unroll
            for (int j = 0; j < 4; ++j) { f[j] = bfb(a[j]); f[4 + j] = bfb(b[j]); }
            xf0[kt] = f;
        }
    }

    f32x2 hold2 = {0.f, 0.f};   // fp32 h for (batch cb, cols colL, colL+1)

// Invariants entering STEP(t): AC = xacc(t); XC = frags(t+1) (in flight).
// STEP(t) issues loads for frags(t+2) into XN and builds AN = xacc(t+1).
#define STEP(T_, XC, XN, AC, AN)                                                \
  {                                                                             \
    const int t = (T_);                                                         \
    BAR();                                                                      \
    const int rb = t & 1, wb = rb ^ 1;                                          \
    short8 ha[4];                                                               \
    _Pragma("unroll")                                                           \
    for (int kt = 0; kt < 4; ++kt)                                              \
        ha[kt] = *(const short8*)(&hbuf[rb][cb][32 * kt + 8 * quad]);           \
    const float m = mlds[t][cb];          /* issued early, hides under MFMAs */ \
    const int tn = (t + 2 < TT) ? t + 2 : TT - 1;                               \
    f32x4 nxa0, nxb0, nxa1, nxb1;                                               \
    if (USE_WS) {                                                               \
        XN[0] = xwp[(size_t)tn * 32];                                           \
        XN[1] = xwp[(size_t)tn * 32 + 16];                                      \
    } else {                                                                    \
        const float* p = xrow + (size_t)tn * TD;                                \
        nxa0 = *(const f32x4*)(p);      nxb0 = *(const f32x4*)(p + 4);          \
        nxa1 = *(const f32x4*)(p + 32); nxb1 = *(const f32x4*)(p + 36);         \
    }                                                                           \
    /* h-MFMAs: 2 tiles x 3 gates x two 2-deep chains, interleaved for ILP */   \
    f32x4 r0A = AC[0][0], z0A = AC[0][1], n0A = zf4;                            \
    f32x4 r1A = AC[1][0], z1A = AC[1][1], n1A = zf4;                            \
    f32x4 r0B = zf4, z0B = zf4, n0B = zf4;                                      \
    f32x4 r1B = zf4, z1B = zf4, n1B = zf4;                                      \
    r0A = MFMA(whh2[0][0][0], ha[0], r0A);                                      \
    z0A = MFMA(whh2[0][1][0], ha[0], z0A);                                      \
    n0A = MFMA(whh2[0][2][0], ha[0], n0A);                                      \
    r1A = MFMA(whh2[1][0][0], ha[0], r1A);                                      \
    z1A = MFMA(whh2[1][1][0], ha[0], z1A);                                      \
    n1A = MFMA(whh2[1][2][0], ha[0], n1A);                                      \
    r0B = MFMA(whh2[0][0][2], ha[2], r0B);                                      \
    z0B = MFMA(whh2[0][1][2], ha[2], z0B);                                      \
    n0B = MFMA(whh2[0][2][2], ha[2], n0B);                                      \
    r1B = MFMA(whh2[1][0][2], ha[2], r1B);                                      \
    z1B = MFMA(whh2[1][1][2], ha[2], z1B);                                      \
    n1B = MFMA(whh2[1][2][2], ha[2], n1B);                                      \
    r0A = MFMA(whh2[0][0][1], ha[1], r0A);                                      \
    z0A = MFMA(whh2[0][1][1], ha[1], z0A);                                      \
    n0A = MFMA(whh2[0][2][1], ha[1], n0A);                                      \
    r1A = MFMA(whh2[1][0][1], ha[1], r1A);                                      \
    z1A = MFMA(whh2[1][1][1], ha[1], z1A);                                      \
    n1A = MFMA(whh2[1][2][1], ha[1], n1A);                                      \
    r0B = MFMA(whh2[0][0][3], ha[3], r0B);                                      \
    z0B = MFMA(whh2[0][1][3], ha[3], z0B);                                      \
    n0B = MFMA(whh2[0][2][3], ha[3], n0B);                                      \
    r1B = MFMA(whh2[1][0][3], ha[3], r1B);                                      \
    z1B = MFMA(whh2[1][1][3], ha[3], z1B);                                      \
    n1B = MFMA(whh2[1][2][3], ha[3], n1B);                                      \
    /* logits for t-1 (rotating wave): rows 0,1 = Wo rows, col = batch */       \
    if (t > 0 && w == ((t - 1) & 3)) {                                          \
        f32x4 lacc = zf4;                                                       \
        _Pragma("unroll")                                                       \
        for (int kt = 0; kt < 4; ++kt) lacc = MFMA(wof[kt], ha[kt], lacc);      \
        if (quad == 0 && c < 4) {                                               \
            f32x2 lo = {lacc[0] + b0o, lacc[1] + b1o};                          \
            *(f32x2*)(out + ((size_t)(Bb + c) * TT + (t - 1)) * 2) = lo;        \
        }                                                                       \
    }                                                                           \
    /* next step's x-gate accumulators (overlap h-chain completion) */          \
    _Pragma("unroll")                                                           \
    for (int Tt = 0; Tt < 2; ++Tt)                                              \
        _Pragma("unroll")                                                       \
        for (int g = 0; g < 3; ++g) {                                           \
            f32x4 a = zf4;                                                      \
            a = MFMA(wih2[Tt][g][0], XC[0], a);                                 \
            a = MFMA(wih2[Tt][g][1], XC[1], a);                                 \
            AN[Tt][g] = a;                                                      \
        }                                                                       \
    /* epilogue: 2 independent chains per lane (tiles 0,1), packed h-write */   \
    {                                                                           \
        float arS0  = ext4(r0A + r0B, s0, s1);                                  \
        float azS0  = ext4(z0A + z0B, s0, s1);                                  \
        float anhS0 = ext4(n0A + n0B, s0, s1);                                  \
        float anxS0 = ext4(AC[0][2],  s0, s1);                                  \
        float arS1  = ext4(r1A + r1B, s0, s1);                                  \
        float azS1  = ext4(z1A + z1B, s0, s1);                                  \
        float anhS1 = ext4(n1A + n1B, s0, s1);                                  \
        float anxS1 = ext4(AC[1][2],  s0, s1);                                  \
        float er0 = __builtin_amdgcn_exp2f(__builtin_fmaf(arS0, -LOG2E, crK[0])); \
        float er1 = __builtin_amdgcn_exp2f(__builtin_fmaf(arS1, -LOG2E, crK[1])); \
        float r0  = __builtin_amdgcn_rcpf(1.0f + er0);                          \
        float r1  = __builtin_amdgcn_rcpf(1.0f + er1);                          \
        float ez0 = __builtin_amdgcn_exp2f(__builtin_fmaf(azS0, -LOG2E, czK[0])); \
        float ez1 = __builtin_amdgcn_exp2f(__builtin_fmaf(azS1, -LOG2E, czK[1])); \
        float z0  = __builtin_amdgcn_rcpf(1.0f + ez0);                          \
        float z1  = __builtin_amdgcn_rcpf(1.0f + ez1);                          \
        float pp0 = (anxS0 + binc[0]) + r0 * (anhS0 + bhnc[0]);                 \
        float pp1 = (anxS1 + binc[1]) + r1 * (anhS1 + bhnc[1]);                 \
        float e20 = __builtin_amdgcn_exp2f(pp0 * (2.0f * LOG2E));               \
        float e21 = __builtin_amdgcn_exp2f(pp1 * (2.0f * LOG2E));               \
        float n0  = __builtin_fmaf(-2.0f, __builtin_amdgcn_rcpf(1.0f + e20), 1.0f); \
        float n1  = __builtin_fmaf(-2.0f, __builtin_amdgcn_rcpf(1.0f + e21), 1.0f); \
        float hn0 = n0 + z0 * (hold2[0] - n0);                                  \
        float hn1 = n1 + z1 * (hold2[1] - n1);                                  \
        hold2[0] = hold2[0] + m * (hn0 - hold2[0]);                             \
        hold2[1] = hold2[1] + m * (hn1 - hold2[1]);                             \
        unsigned pk = (unsigned)(unsigned short)bfb(hold2[0]) |                 \
                      ((unsigned)(unsigned short)bfb(hold2[1]) << 16);          \
        *(unsigned*)(&hbuf[wb][cb][colL]) = pk;                                 \
    }                                                                           \
    if (!USE_WS) {                                                              \
        short8 f0, f1;                                                          \
        _Pragma("unroll")                                                       \
        for (int j = 0; j < 4; ++j) { f0[j] = bfb(nxa0[j]); f0[4+j] = bfb(nxb0[j]); \
                                      f1[j] = bfb(nxa1[j]); f1[4+j] = bfb(nxb1[j]); } \
        XN[0] = f0; XN[1] = f1;                                                 \
    }                                                                           \
  }

    for (int t2 = 0; t2 < TT; t2 += 2) {
        STEP(t2,     xf0, xf1, xacA, xacB);
        STEP(t2 + 1, xf1, xf0, xacB, xacA);
    }
#undef STEP

    // flush logits for t = TT-1 (h(TT-1) sits in hbuf[0])
    BAR();
    if (w == 3) {
        short8 ha[4];
        #pragma unroll
        for (int kt = 0; kt < 4; ++kt)
            ha[kt] = *(const short8*)(&hbuf[0][cb][32 * kt + 8 * quad]);
        f32x4 lacc = zf4;
        #pragma unroll
        for (int kt = 0; kt < 4; ++kt) lacc = MFMA(wof[kt], ha[kt], lacc);
        if (quad == 0 && c < 4) {
            f32x2 lo = {lacc[0] + b0o, lacc[1] + b1o};
            *(f32x2*)(out + ((size_t)(Bb + c) * TT + (TT - 1)) * 2) = lo;
        }
    }
}

extern "C" void kernel_launch(void* const* d_in, const int* in_sizes, int n_in,
                              void* d_out, int out_size, void* d_ws, size_t ws_size,
                              hipStream_t stream) {
    const float* x    = (const float*)d_in[0];
    const float* mask = (const float*)d_in[1];
    const float* w_ih = (const float*)d_in[2];
    const float* w_hh = (const float*)d_in[3];
    const float* b_ih = (const float*)d_in[4];
    const float* b_hh = (const float*)d_in[5];
    const float* Wo   = (const float*)d_in[6];
    const float* bo   = (const float*)d_in[7];
    float* out = (float*)d_out;
    (void)in_sizes; (void)n_in; (void)out_size;

    const size_t nfrag = (size_t)(TB / NR) * TT * 2 * 16;       // 4.19M short8
    const size_t need  = nfrag * sizeof(short8);                // 67.1 MB
    if (ws_size >= need) {
        short8* xw = (short8*)d_ws;
        xswz<<<(int)(nfrag / 256), 256, 0, stream>>>(x, xw);
        gru_mfma<true><<<TB / NR, 256, 0, stream>>>(x, xw, mask, w_ih, w_hh,
                                                    b_ih, b_hh, Wo, bo, out);
    } else {
        gru_mfma<false><<<TB / NR, 256, 0, stream>>>(x, (const short8*)nullptr, mask,
                                                     w_ih, w_hh, b_ih, b_hh, Wo, bo, out);
    }
}

// Round 7
// 775.004 us; speedup vs baseline: 1.1446x; 1.1446x over previous
//
#include <hip/hip_runtime.h>

#define TB 512   // batch
#define TT 1024  // time
#define TD 64    // input dim
#define TH 128   // hidden
#define NR 4     // batch rows per block -> 128 blocks

typedef __attribute__((ext_vector_type(8))) short short8;  // 8 bf16 (4 VGPRs)
typedef __attribute__((ext_vector_type(4))) float f32x4;   // MFMA C/D
typedef __attribute__((ext_vector_type(2))) float f32x2;

#define LOG2E 1.44269504f

// fp32 -> bf16 bits, round-to-nearest-even
__device__ __forceinline__ short bfb(float f) {
    unsigned u = __builtin_bit_cast(unsigned, f);
    u = (u + 0x7FFFu + ((u >> 16) & 1u)) >> 16;
    return (short)u;
}

// Barrier with LDS-only drain: global loads/stores stay in flight across it.
#define BAR() asm volatile("s_waitcnt lgkmcnt(0)\n\ts_barrier" ::: "memory")

#define MFMA(a, b, cc) __builtin_amdgcn_mfma_f32_16x16x32_bf16(a, b, cc, 0, 0, 0)

// select v[r], r = s1*2 + s0, via 3 cndmasks (bools precomputed per lane)
__device__ __forceinline__ float ext4(f32x4 v, bool s0, bool s1) {
    float a = s0 ? v[1] : v[0];
    float b = s0 ? v[3] : v[2];
    return s1 ? b : a;
}

// ---------------- phase 1: x -> bf16 fragment order (compact, 4 rows) -------
// ws layout (short8 units): [blk 0..127][t][kt 0..1][e 0..15], e = c*4 + quad
// holds x[blk*4 + c][t][32*kt + 8*quad + j], j=0..7
__global__ __launch_bounds__(256)
void xswz(const float* __restrict__ x, short8* __restrict__ ws) {
    int gid = blockIdx.x * 256 + threadIdx.x;   // 128*1024*2*16 = 4.19M
    int e   = gid & 15;
    int kt  = (gid >> 4) & 1;
    int t   = (gid >> 5) & (TT - 1);
    int blk = gid >> 15;
    int c = e >> 2, quad = e & 3;
    const float* p = x + ((size_t)(blk * NR + c) * TT + t) * TD + 32 * kt + 8 * quad;
    f32x4 a = *(const f32x4*)p;
    f32x4 b = *(const f32x4*)(p + 4);
    short8 f;
    #pragma unroll
    for (int j = 0; j < 4; ++j) { f[j] = bfb(a[j]); f[4 + j] = bfb(b[j]); }
    ws[gid] = f;
}

// ---------------- phase 2: the scan -----------------------------------------
// 128 blocks x 512 threads (8 waves, 2/SIMD -- load-bearing TLP, see R6).
// Block owns 4 batch rows. TRANSPOSED MFMA (C' = W_tile * h^T) with
// REPLICATED B-operand: all lanes read batch row (c&3), so lane (c,q)'s
// accumulator quad is replicated 4x across c-groups; lane owns the real value
// at reg r = c>>2: (gate col 16w+4q+(c>>2), batch c&3). Epilogue is one chain
// per lane via 3-cndmask extract; no LDS exchange.
// This round: x-MFMAs for t+1 issue BEFORE the h-MFMAs (fills the post-barrier
// ha ds_read latency window); mask and anx are carried in registers across
// steps (no post-barrier LDS read / no in-path extraction for them).
template <bool USE_WS>
__global__ __launch_bounds__(512, 1)
void gru_mfma(const float* __restrict__ x, const short8* __restrict__ xw,
              const float* __restrict__ mask,
              const float* __restrict__ w_ih, const float* __restrict__ w_hh,
              const float* __restrict__ b_ih, const float* __restrict__ b_hh,
              const float* __restrict__ Wo, const float* __restrict__ bo,
              float* __restrict__ out)
{
    __shared__ short hbuf[2][4][144];     // h(t) bf16, rows 0..3; 288B row
    __shared__ float mlds[TT][NR];        // mask slice (16 KB)

    const int tid  = threadIdx.x;
    const int w    = tid >> 6;
    const int lane = tid & 63;
    const int c    = lane & 15;
    const int quad = lane >> 4;
    const int Bb   = blockIdx.x * NR;
    const int cb   = c & 3;               // batch row this lane tracks
    const bool s0  = ((c >> 2) & 1) != 0; // extract selectors for reg c>>2
    const bool s1  = ((c >> 3) & 1) != 0;

    // ---- one-time staging ----
    for (int i = tid; i < TT * NR; i += 512) {
        int t = i >> 2, b = i & 3;
        mlds[t][b] = mask[(size_t)(Bb + b) * TT + t];
    }
    for (int i = tid; i < 2 * 4 * 144; i += 512) (&hbuf[0][0][0])[i] = 0;
    __syncthreads();                      // mlds/hbuf visible for prologue reads

    const int jj = 16 * w + c;            // weight-fragment row/col key

    // ---- weights -> bf16 fragments in registers ----
    short8 whh[3][4], wih[3][2], wof[4];
    {
        const int gg[3] = {jj, TH + jj, 2 * TH + jj};
        #pragma unroll
        for (int g = 0; g < 3; ++g) {
            #pragma unroll
            for (int kt = 0; kt < 4; ++kt) {
                const float* p = w_hh + (size_t)gg[g] * TH + 32 * kt + 8 * quad;
                short8 f;
                #pragma unroll
                for (int j = 0; j < 8; ++j) f[j] = bfb(p[j]);
                whh[g][kt] = f;
            }
            #pragma unroll
            for (int kt = 0; kt < 2; ++kt) {
                const float* p = w_ih + (size_t)gg[g] * TD + 32 * kt + 8 * quad;
                short8 f;
                #pragma unroll
                for (int j = 0; j < 8; ++j) f[j] = bfb(p[j]);
                wih[g][kt] = f;
            }
        }
        #pragma unroll
        for (int kt = 0; kt < 4; ++kt) {
            short8 f = {0,0,0,0,0,0,0,0};
            if (c < 2) {
                const float* p = Wo + (size_t)c * TH + 32 * kt + 8 * quad;
                #pragma unroll
                for (int j = 0; j < 8; ++j) f[j] = bfb(p[j]);
            }
            wof[kt] = f;
        }
    }

    // epilogue constants for THIS lane's gate column myc
    const int myc = 16 * w + 4 * quad + (c >> 2);
    const float crK = -LOG2E * (b_ih[myc] + b_hh[myc]);
    const float czK = -LOG2E * (b_ih[TH + myc] + b_hh[TH + myc]);
    const float bin = b_ih[2 * TH + myc];
    const float bhn = b_hh[2 * TH + myc];
    const float b0o = bo[0], b1o = bo[1];

    const f32x4 zf4 = {0.f, 0.f, 0.f, 0.f};

    // x access bases — replicated across c-groups (row cb)
    const short8* xwp  = xw + (size_t)blockIdx.x * (TT * 32) + (cb * 4 + quad);
    const float*  xrow = x + (size_t)(Bb + cb) * TT * TD + 8 * quad;

    short8 xf0[2], xf1[2];
    // frags(0) -> xf0
    if (USE_WS) {
        xf0[0] = xwp[0];
        xf0[1] = xwp[16];
    } else {
        #pragma unroll
        for (int kt = 0; kt < 2; ++kt) {
            f32x4 a = *(const f32x4*)(xrow + 32 * kt);
            f32x4 b = *(const f32x4*)(xrow + 32 * kt + 4);
            short8 f;
            #pragma unroll
            for (int j = 0; j < 4; ++j) { f[j] = bfb(a[j]); f[4 + j] = bfb(b[j]); }
            xf0[kt] = f;
        }
    }

    // xacc(0) from frags(0)  (W_ih as A-operand, x as B-operand)
    f32x4 xacA[3], xacB[3];
    #pragma unroll
    for (int g = 0; g < 3; ++g) {
        f32x4 a = zf4;
        a = MFMA(wih[g][0], xf0[0], a);
        a = MFMA(wih[g][1], xf0[1], a);
        xacA[g] = a;
    }

    // carried scalars: anx extraction + mask, one step ahead
    float axA = ext4(xacA[2], s0, s1), axB = 0.0f;
    float mA  = mlds[0][cb],           mB  = 0.0f;

    // frags(1) -> xf0
    if (USE_WS) {
        xf0[0] = xwp[32];
        xf0[1] = xwp[48];
    } else {
        const float* p = xrow + (size_t)1 * TD;
        #pragma unroll
        for (int kt = 0; kt < 2; ++kt) {
            f32x4 a = *(const f32x4*)(p + 32 * kt);
            f32x4 b = *(const f32x4*)(p + 32 * kt + 4);
            short8 f;
            #pragma unroll
            for (int j = 0; j < 4; ++j) { f[j] = bfb(a[j]); f[4 + j] = bfb(b[j]); }
            xf0[kt] = f;
        }
    }

    float hold = 0.0f;   // fp32 h for (batch=cb, col=myc)

// Invariants entering STEP(t): AC = xacc(t); XC = frags(t+1) (in flight);
// M_ = mask(t); AX_ = ext4(AC[2]) precomputed. STEP(t) issues loads for
// frags(t+2) into XN, builds AN = xacc(t+1), sets MN_ = mask(t+1) and
// AXN_ = ext4(AN[2]).
#define STEP(T_, XC, XN, AC, AN, M_, MN_, AX_, AXN_)                            \
  {                                                                             \
    const int t = (T_);                                                         \
    BAR();                                                                      \
    const int rb = t & 1, wb = rb ^ 1;                                          \
    short8 ha[4];                                                               \
    _Pragma("unroll")                                                           \
    for (int kt = 0; kt < 4; ++kt)                                              \
        ha[kt] = *(const short8*)(&hbuf[rb][cb][32 * kt + 8 * quad]);           \
    const int tn1 = (t + 1 < TT) ? t + 1 : TT - 1;                              \
    MN_ = mlds[tn1][cb];                 /* mask(t+1), carried in a register */ \
    const int tn = (t + 2 < TT) ? t + 2 : TT - 1;                               \
    f32x4 nxa0, nxb0, nxa1, nxb1;                                               \
    if (USE_WS) {                                                               \
        XN[0] = xwp[(size_t)tn * 32];                                           \
        XN[1] = xwp[(size_t)tn * 32 + 16];                                      \
    } else {                                                                    \
        const float* p = xrow + (size_t)tn * TD;                                \
        nxa0 = *(const f32x4*)(p);      nxb0 = *(const f32x4*)(p + 4);          \
        nxa1 = *(const f32x4*)(p + 32); nxb1 = *(const f32x4*)(p + 36);         \
    }                                                                           \
    /* x-MFMAs for t+1 FIRST: operands pre-barrier-ready; their issue fills */  \
    /* the ha ds_read latency window */                                         \
    _Pragma("unroll")                                                           \
    for (int g = 0; g < 3; ++g) {                                               \
        f32x4 a = zf4;                                                          \
        a = MFMA(wih[g][0], XC[0], a);                                          \
        a = MFMA(wih[g][1], XC[1], a);                                          \
        AN[g] = a;                                                              \
    }                                                                           \
    /* h-MFMAs (transposed): two 2-deep chains per gate */                      \
    f32x4 rA = AC[0], zA = AC[1], nA = zf4;                                     \
    f32x4 rB = zf4, zB = zf4, nB = zf4;                                         \
    rA = MFMA(whh[0][0], ha[0], rA);                                            \
    zA = MFMA(whh[1][0], ha[0], zA);                                            \
    nA = MFMA(whh[2][0], ha[0], nA);                                            \
    rB = MFMA(whh[0][2], ha[2], rB);                                            \
    zB = MFMA(whh[1][2], ha[2], zB);                                            \
    nB = MFMA(whh[2][2], ha[2], nB);                                            \
    rA = MFMA(whh[0][1], ha[1], rA);                                            \
    zA = MFMA(whh[1][1], ha[1], zA);                                            \
    nA = MFMA(whh[2][1], ha[1], nA);                                            \
    rB = MFMA(whh[0][3], ha[3], rB);                                            \
    zB = MFMA(whh[1][3], ha[3], zB);                                            \
    nB = MFMA(whh[2][3], ha[3], nB);                                            \
    /* logits for t-1 (rotating wave): rows 0,1 = Wo rows, col = batch */       \
    if (t > 0 && w == ((t - 1) & 7)) {                                          \
        f32x4 lacc = zf4;                                                       \
        _Pragma("unroll")                                                       \
        for (int kt = 0; kt < 4; ++kt) lacc = MFMA(wof[kt], ha[kt], lacc);      \
        if (quad == 0 && c < 4) {                                               \
            f32x2 lo = {lacc[0] + b0o, lacc[1] + b1o};                          \
            *(f32x2*)(out + ((size_t)(Bb + c) * TT + (t - 1)) * 2) = lo;        \
        }                                                                       \
    }                                                                           \
    AXN_ = ext4(AN[2], s0, s1);          /* next step's anx, extracted early */ \
    /* scalar epilogue: this lane's (batch cb, col myc) = reg c>>2 */           \
    {                                                                           \
        float arS  = ext4(rA + rB, s0, s1);                                     \
        float azS  = ext4(zA + zB, s0, s1);                                     \
        float anhS = ext4(nA + nB, s0, s1);                                     \
        float er = __builtin_amdgcn_exp2f(__builtin_fmaf(arS, -LOG2E, crK));    \
        float r  = __builtin_amdgcn_rcpf(1.0f + er);                            \
        float ez = __builtin_amdgcn_exp2f(__builtin_fmaf(azS, -LOG2E, czK));    \
        float z  = __builtin_amdgcn_rcpf(1.0f + ez);                            \
        float pp = (AX_ + bin) + r * (anhS + bhn);                              \
        float e2 = __builtin_amdgcn_exp2f(pp * (2.0f * LOG2E));                 \
        float n  = __builtin_fmaf(-2.0f, __builtin_amdgcn_rcpf(1.0f + e2), 1.0f); \
        float hn = n + z * (hold - n);                                          \
        hold = hold + M_ * (hn - hold);                                         \
        hbuf[wb][cb][myc] = bfb(hold);                                          \
    }                                                                           \
    if (!USE_WS) {                                                              \
        short8 f0, f1;                                                          \
        _Pragma("unroll")                                                       \
        for (int j = 0; j < 4; ++j) { f0[j] = bfb(nxa0[j]); f0[4+j] = bfb(nxb0[j]); \
                                      f1[j] = bfb(nxa1[j]); f1[4+j] = bfb(nxb1[j]); } \
        XN[0] = f0; XN[1] = f1;                                                 \
    }                                                                           \
  }

    for (int t2 = 0; t2 < TT; t2 += 2) {
        STEP(t2,     xf0, xf1, xacA, xacB, mA, mB, axA, axB);
        STEP(t2 + 1, xf1, xf0, xacB, xacA, mB, mA, axB, axA);
    }
#undef STEP

    // flush logits for t = TT-1 (h(TT-1) sits in hbuf[0])
    BAR();
    if (w == 7) {
        short8 ha[4];
        #pragma unroll
        for (int kt = 0; kt < 4; ++kt)
            ha[kt] = *(const short8*)(&hbuf[0][cb][32 * kt + 8 * quad]);
        f32x4 lacc = zf4;
        #pragma unroll
        for (int kt = 0; kt < 4; ++kt) lacc = MFMA(wof[kt], ha[kt], lacc);
        if (quad == 0 && c < 4) {
            f32x2 lo = {lacc[0] + b0o, lacc[1] + b1o};
            *(f32x2*)(out + ((size_t)(Bb + c) * TT + (TT - 1)) * 2) = lo;
        }
    }
}

extern "C" void kernel_launch(void* const* d_in, const int* in_sizes, int n_in,
                              void* d_out, int out_size, void* d_ws, size_t ws_size,
                              hipStream_t stream) {
    const float* x    = (const float*)d_in[0];
    const float* mask = (const float*)d_in[1];
    const float* w_ih = (const float*)d_in[2];
    const float* w_hh = (const float*)d_in[3];
    const float* b_ih = (const float*)d_in[4];
    const float* b_hh = (const float*)d_in[5];
    const float* Wo   = (const float*)d_in[6];
    const float* bo   = (const float*)d_in[7];
    float* out = (float*)d_out;
    (void)in_sizes; (void)n_in; (void)out_size;

    const size_t nfrag = (size_t)(TB / NR) * TT * 2 * 16;       // 4.19M short8
    const size_t need  = nfrag * sizeof(short8);                // 67.1 MB
    if (ws_size >= need) {
        short8* xw = (short8*)d_ws;
        xswz<<<(int)(nfrag / 256), 256, 0, stream>>>(x, xw);
        gru_mfma<true><<<TB / NR, 512, 0, stream>>>(x, xw, mask, w_ih, w_hh,
                                                    b_ih, b_hh, Wo, bo, out);
    } else {
        gru_mfma<false><<<TB / NR, 512, 0, stream>>>(x, (const short8*)nullptr, mask,
                                                     w_ih, w_hh, b_ih, b_hh, Wo, bo, out);
    }
}

// Round 8
// 744.199 us; speedup vs baseline: 1.1920x; 1.0414x over previous
//
#include <hip/hip_runtime.h>

#define TB 512   // batch
#define TT 1024  // time
#define TD 64    // input dim
#define TH 128   // hidden
#define NR 4     // batch rows per block -> 128 blocks

typedef __attribute__((ext_vector_type(8))) short short8;  // 8 bf16 (4 VGPRs)
typedef __attribute__((ext_vector_type(4))) float f32x4;   // MFMA C/D
typedef __attribute__((ext_vector_type(2))) float f32x2;

#define LOG2E 1.44269504f

// fp32 -> bf16 bits, round-to-nearest-even
__device__ __forceinline__ short bfb(float f) {
    unsigned u = __builtin_bit_cast(unsigned, f);
    u = (u + 0x7FFFu + ((u >> 16) & 1u)) >> 16;
    return (short)u;
}

// Barrier with LDS-only drain: global loads/stores stay in flight across it.
#define BAR() asm volatile("s_waitcnt lgkmcnt(0)\n\ts_barrier" ::: "memory")

#define MFMA(a, b, cc) __builtin_amdgcn_mfma_f32_16x16x32_bf16(a, b, cc, 0, 0, 0)

// select v[r], r = s1*2 + s0, via 3 cndmasks (bools precomputed per lane)
__device__ __forceinline__ float ext4(f32x4 v, bool s0, bool s1) {
    float a = s0 ? v[1] : v[0];
    float b = s0 ? v[3] : v[2];
    return s1 ? b : a;
}

// ---------------- phase 1: x -> bf16 fragment order (coalesced) -------------
// Output layout UNCHANGED (short8 units): ws[blk][t][kt][e], e = c*4 + quad,
// holding x[blk*4 + c][t][32*kt + 8*quad + j], j=0..7.
// NEW thread mapping: one wave owns (blk, c, 8 consecutive t). Lane l:
//   t = t0 + (l>>3), kt = (l>>2)&1, quad = l&3.
// 8 consecutive lanes read one full 256B x-row contiguously -> the wave
// streams 2KB of perfectly coalesced reads (old mapping scattered lanes
// across batch rows at 256KB stride: ~4-8x over-fetch, ~150us).
__global__ __launch_bounds__(256)
void xswz(const float* __restrict__ x, short8* __restrict__ ws) {
    int gid = blockIdx.x * 256 + threadIdx.x;
    int W   = gid >> 6;                    // wave id, 0..65535
    int l   = gid & 63;
    int blk = W >> 9;                      // 512 waves per blk (4c x 128 tgrp)
    int c   = (W >> 7) & 3;
    int t   = (W & 127) * 8 + (l >> 3);
    int kt  = (l >> 2) & 1;
    int quad= l & 3;
    const float* p = x + ((size_t)(blk * NR + c) * TT + t) * TD + 32 * kt + 8 * quad;
    f32x4 a = *(const f32x4*)p;
    f32x4 b = *(const f32x4*)(p + 4);
    short8 f;
    #pragma unroll
    for (int j = 0; j < 4; ++j) { f[j] = bfb(a[j]); f[4 + j] = bfb(b[j]); }
    ws[(((size_t)blk * TT + t) * 2 + kt) * 16 + c * 4 + quad] = f;
}

// ---------------- phase 2: the scan (R5-exact, best known: 588us) -----------
// 128 blocks x 512 threads. Block owns 4 batch rows.
// TRANSPOSED MFMA (C' = W_tile * h^T) with REPLICATED B-operand: all lanes
// read batch row (c&3), so lane (c,q)'s accumulator quad is replicated 4x
// across c-groups. Lane (c,q) therefore owns the REAL value at reg r = c>>2:
// (gate col 16w+4q+(c>>2), batch c&3) -- 64 lanes x 1 value = the wave's full
// 16-col x 4-batch tile. Epilogue is ONE chain per lane (3-cndmask extract),
// no LDS exchange at all.
template <bool USE_WS>
__global__ __launch_bounds__(512, 1)
void gru_mfma(const float* __restrict__ x, const short8* __restrict__ xw,
              const float* __restrict__ mask,
              const float* __restrict__ w_ih, const float* __restrict__ w_hh,
              const float* __restrict__ b_ih, const float* __restrict__ b_hh,
              const float* __restrict__ Wo, const float* __restrict__ bo,
              float* __restrict__ out)
{
    __shared__ short hbuf[2][4][144];     // h(t) bf16, rows 0..3; 288B row
    __shared__ float mlds[TT][NR];        // mask slice (16 KB)

    const int tid  = threadIdx.x;
    const int w    = tid >> 6;
    const int lane = tid & 63;
    const int c    = lane & 15;
    const int quad = lane >> 4;
    const int Bb   = blockIdx.x * NR;
    const int cb   = c & 3;               // batch row this lane tracks
    const bool s0  = ((c >> 2) & 1) != 0; // extract selectors for reg c>>2
    const bool s1  = ((c >> 3) & 1) != 0;

    // ---- one-time staging ----
    for (int i = tid; i < TT * NR; i += 512) {
        int t = i >> 2, b = i & 3;
        mlds[t][b] = mask[(size_t)(Bb + b) * TT + t];
    }
    for (int i = tid; i < 2 * 4 * 144; i += 512) (&hbuf[0][0][0])[i] = 0;

    const int jj = 16 * w + c;            // weight-fragment row/col key

    // ---- weights -> bf16 fragments in registers ----
    short8 whh[3][4], wih[3][2], wof[4];
    {
        const int gg[3] = {jj, TH + jj, 2 * TH + jj};
        #pragma unroll
        for (int g = 0; g < 3; ++g) {
            #pragma unroll
            for (int kt = 0; kt < 4; ++kt) {
                const float* p = w_hh + (size_t)gg[g] * TH + 32 * kt + 8 * quad;
                short8 f;
                #pragma unroll
                for (int j = 0; j < 8; ++j) f[j] = bfb(p[j]);
                whh[g][kt] = f;
            }
            #pragma unroll
            for (int kt = 0; kt < 2; ++kt) {
                const float* p = w_ih + (size_t)gg[g] * TD + 32 * kt + 8 * quad;
                short8 f;
                #pragma unroll
                for (int j = 0; j < 8; ++j) f[j] = bfb(p[j]);
                wih[g][kt] = f;
            }
        }
        #pragma unroll
        for (int kt = 0; kt < 4; ++kt) {
            short8 f = {0,0,0,0,0,0,0,0};
            if (c < 2) {
                const float* p = Wo + (size_t)c * TH + 32 * kt + 8 * quad;
                #pragma unroll
                for (int j = 0; j < 8; ++j) f[j] = bfb(p[j]);
            }
            wof[kt] = f;
        }
    }

    // epilogue constants for THIS lane's gate column myc (scalar)
    const int myc = 16 * w + 4 * quad + (c >> 2);
    const float crK = -LOG2E * (b_ih[myc] + b_hh[myc]);
    const float czK = -LOG2E * (b_ih[TH + myc] + b_hh[TH + myc]);
    const float bin = b_ih[2 * TH + myc];
    const float bhn = b_hh[2 * TH + myc];
    const float b0o = bo[0], b1o = bo[1];

    const f32x4 zf4 = {0.f, 0.f, 0.f, 0.f};

    // x access bases — replicated across c-groups (row c&3), coalesced
    const short8* xwp  = xw + (size_t)blockIdx.x * (TT * 32) + (cb * 4 + quad);
    const float*  xrow = x + (size_t)(Bb + cb) * TT * TD + 8 * quad;

    short8 xf0[2], xf1[2];
    // frags(0) -> xf0
    if (USE_WS) {
        xf0[0] = xwp[0];
        xf0[1] = xwp[16];
    } else {
        #pragma unroll
        for (int kt = 0; kt < 2; ++kt) {
            f32x4 a = *(const f32x4*)(xrow + 32 * kt);
            f32x4 b = *(const f32x4*)(xrow + 32 * kt + 4);
            short8 f;
            #pragma unroll
            for (int j = 0; j < 4; ++j) { f[j] = bfb(a[j]); f[4 + j] = bfb(b[j]); }
            xf0[kt] = f;
        }
    }

    // xacc(0) from frags(0)  (W_ih as A-operand, x as B-operand)
    f32x4 xacA[3], xacB[3];
    #pragma unroll
    for (int g = 0; g < 3; ++g) {
        f32x4 a = zf4;
        a = MFMA(wih[g][0], xf0[0], a);
        a = MFMA(wih[g][1], xf0[1], a);
        xacA[g] = a;
    }

    // frags(1) -> xf0
    if (USE_WS) {
        xf0[0] = xwp[32];
        xf0[1] = xwp[48];
    } else {
        const float* p = xrow + (size_t)1 * TD;
        #pragma unroll
        for (int kt = 0; kt < 2; ++kt) {
            f32x4 a = *(const f32x4*)(p + 32 * kt);
            f32x4 b = *(const f32x4*)(p + 32 * kt + 4);
            short8 f;
            #pragma unroll
            for (int j = 0; j < 4; ++j) { f[j] = bfb(a[j]); f[4 + j] = bfb(b[j]); }
            xf0[kt] = f;
        }
    }

    float hold = 0.0f;   // fp32 h for (batch=cb, col=myc)

// Invariants entering STEP(t): AC = xacc(t); XC = frags(t+1) (in flight).
// STEP(t) issues loads for frags(t+2) into XN and builds AN = xacc(t+1).
#define STEP(T, XC, XN, AC, AN)                                                 \
  {                                                                             \
    const int t = (T);                                                          \
    BAR();                                                                      \
    const int rb = t & 1, wb = rb ^ 1;                                          \
    short8 ha[4];                                                               \
    _Pragma("unroll")                                                           \
    for (int kt = 0; kt < 4; ++kt)                                              \
        ha[kt] = *(const short8*)(&hbuf[rb][cb][32 * kt + 8 * quad]);           \
    const float m = mlds[t][cb];          /* issued early, hides under MFMAs */ \
    const int tn = (t + 2 < TT) ? t + 2 : TT - 1;                               \
    f32x4 nxa0, nxb0, nxa1, nxb1;                                               \
    if (USE_WS) {                                                               \
        XN[0] = xwp[(size_t)tn * 32];                                           \
        XN[1] = xwp[(size_t)tn * 32 + 16];                                      \
    } else {                                                                    \
        const float* p = xrow + (size_t)tn * TD;                                \
        nxa0 = *(const f32x4*)(p);      nxb0 = *(const f32x4*)(p + 4);          \
        nxa1 = *(const f32x4*)(p + 32); nxb1 = *(const f32x4*)(p + 36);         \
    }                                                                           \
    /* h-MFMAs (transposed): two 2-deep chains per gate */                      \
    f32x4 rA = AC[0], zA = AC[1], nA = zf4;                                     \
    f32x4 rB = zf4, zB = zf4, nB = zf4;                                         \
    rA = MFMA(whh[0][0], ha[0], rA);                                            \
    zA = MFMA(whh[1][0], ha[0], zA);                                            \
    nA = MFMA(whh[2][0], ha[0], nA);                                            \
    rB = MFMA(whh[0][2], ha[2], rB);                                            \
    zB = MFMA(whh[1][2], ha[2], zB);                                            \
    nB = MFMA(whh[2][2], ha[2], nB);                                            \
    rA = MFMA(whh[0][1], ha[1], rA);                                            \
    zA = MFMA(whh[1][1], ha[1], zA);                                            \
    nA = MFMA(whh[2][1], ha[1], nA);                                            \
    rB = MFMA(whh[0][3], ha[3], rB);                                            \
    zB = MFMA(whh[1][3], ha[3], zB);                                            \
    nB = MFMA(whh[2][3], ha[3], nB);                                            \
    /* logits for t-1 (rotating wave): rows 0,1 = Wo rows, col = batch */       \
    if (t > 0 && w == ((t - 1) & 7)) {                                          \
        f32x4 lacc = zf4;                                                       \
        _Pragma("unroll")                                                       \
        for (int kt = 0; kt < 4; ++kt) lacc = MFMA(wof[kt], ha[kt], lacc);      \
        if (quad == 0 && c < 4) {                                               \
            f32x2 lo = {lacc[0] + b0o, lacc[1] + b1o};                          \
            *(f32x2*)(out + ((size_t)(Bb + c) * TT + (t - 1)) * 2) = lo;        \
        }                                                                       \
    }                                                                           \
    /* next step's x-gate accumulators (overlap h-chain completion) */          \
    _Pragma("unroll")                                                           \
    for (int g = 0; g < 3; ++g) {                                               \
        f32x4 a = zf4;                                                          \
        a = MFMA(wih[g][0], XC[0], a);                                          \
        a = MFMA(wih[g][1], XC[1], a);                                          \
        AN[g] = a;                                                              \
    }                                                                           \
    /* scalar epilogue: this lane's (batch cb, col myc) = reg c>>2 */           \
    {                                                                           \
        float arS  = ext4(rA + rB, s0, s1);                                     \
        float azS  = ext4(zA + zB, s0, s1);                                     \
        float anhS = ext4(nA + nB, s0, s1);                                     \
        float anxS = ext4(AC[2],   s0, s1);                                     \
        float er = __builtin_amdgcn_exp2f(__builtin_fmaf(arS, -LOG2E, crK));    \
        float r  = __builtin_amdgcn_rcpf(1.0f + er);                            \
        float ez = __builtin_amdgcn_exp2f(__builtin_fmaf(azS, -LOG2E, czK));    \
        float z  = __builtin_amdgcn_rcpf(1.0f + ez);                            \
        float pp = (anxS + bin) + r * (anhS + bhn);                             \
        float e2 = __builtin_amdgcn_exp2f(pp * (2.0f * LOG2E));                 \
        float n  = __builtin_fmaf(-2.0f, __builtin_amdgcn_rcpf(1.0f + e2), 1.0f); \
        float hn = n + z * (hold - n);                                          \
        hold = hold + m * (hn - hold);                                          \
        hbuf[wb][cb][myc] = bfb(hold);                                          \
    }                                                                           \
    if (!USE_WS) {                                                              \
        short8 f0, f1;                                                          \
        _Pragma("unroll")                                                       \
        for (int j = 0; j < 4; ++j) { f0[j] = bfb(nxa0[j]); f0[4+j] = bfb(nxb0[j]); \
                                      f1[j] = bfb(nxa1[j]); f1[4+j] = bfb(nxb1[j]); } \
        XN[0] = f0; XN[1] = f1;                                                 \
    }                                                                           \
  }

    for (int t2 = 0; t2 < TT; t2 += 2) {
        STEP(t2,     xf0, xf1, xacA, xacB);
        STEP(t2 + 1, xf1, xf0, xacB, xacA);
    }
#undef STEP

    // flush logits for t = TT-1 (h(TT-1) sits in hbuf[0])
    BAR();
    if (w == 7) {
        short8 ha[4];
        #pragma unroll
        for (int kt = 0; kt < 4; ++kt)
            ha[kt] = *(const short8*)(&hbuf[0][cb][32 * kt + 8 * quad]);
        f32x4 lacc = zf4;
        #pragma unroll
        for (int kt = 0; kt < 4; ++kt) lacc = MFMA(wof[kt], ha[kt], lacc);
        if (quad == 0 && c < 4) {
            f32x2 lo = {lacc[0] + b0o, lacc[1] + b1o};
            *(f32x2*)(out + ((size_t)(Bb + c) * TT + (TT - 1)) * 2) = lo;
        }
    }
}

extern "C" void kernel_launch(void* const* d_in, const int* in_sizes, int n_in,
                              void* d_out, int out_size, void* d_ws, size_t ws_size,
                              hipStream_t stream) {
    const float* x    = (const float*)d_in[0];
    const float* mask = (const float*)d_in[1];
    const float* w_ih = (const float*)d_in[2];
    const float* w_hh = (const float*)d_in[3];
    const float* b_ih = (const float*)d_in[4];
    const float* b_hh = (const float*)d_in[5];
    const float* Wo   = (const float*)d_in[6];
    const float* bo   = (const float*)d_in[7];
    float* out = (float*)d_out;
    (void)in_sizes; (void)n_in; (void)out_size;

    const size_t nfrag = (size_t)(TB / NR) * TT * 2 * 16;       // 4.19M short8
    const size_t need  = nfrag * sizeof(short8);                // 67.1 MB
    if (ws_size >= need) {
        short8* xw = (short8*)d_ws;
        xswz<<<(int)(nfrag / 256), 256, 0, stream>>>(x, xw);
        gru_mfma<true><<<TB / NR, 512, 0, stream>>>(x, xw, mask, w_ih, w_hh,
                                                    b_ih, b_hh, Wo, bo, out);
    } else {
        gru_mfma<false><<<TB / NR, 512, 0, stream>>>(x, (const short8*)nullptr, mask,
                                                     w_ih, w_hh, b_ih, b_hh, Wo, bo, out);
    }
}